// Round 10
// baseline (378.964 us; speedup 1.0000x reference)
//
#include <hip/hip_runtime.h>
#include <hip/hip_bf16.h>

// GAT. h = x@W^T via bf16 MFMA (16x16x32), no LDS; att coeffs fused into
// k_lin epilogue. CSR by dst via 2-level bucketed counting sort. k_agg:
// wave per dst; 4x16-lane groups, dwordx4 row gathers (4 edges per VMEM
// instr), per-chunk LDS-staged edge weights (exp once/edge), fused graph
// pooling. BN over graphs; FC 128->32.  H=2 x C=64.
// Softmax max-shift skipped (|e| small, exp safe in fp32).
// All __shfl ops run with full exec (convergent) — never in divergent branches.

#define BKT_SHIFT 8              // 256 nodes per bucket
#define BKT_MASK  255
#define BKT_CAP   14336          // LDS staging records in k_bsort (56 KB)
#define BIN_TILE  4096           // edges per block in k_b0/k_bin

typedef __attribute__((ext_vector_type(8))) short bf16x8;
typedef __attribute__((ext_vector_type(4))) float f32x4;

static __device__ __forceinline__ float bf2f(unsigned short u) {
    union { unsigned int i; float f; } c; c.i = ((unsigned int)u) << 16; return c.f;
}
static __device__ __forceinline__ unsigned short f2bf(float f) {
    unsigned int b = __builtin_bit_cast(unsigned int, f);
    return (unsigned short)((b >> 16) + ((b >> 15) & 1));
}

// ---------------- zero fill ----------------
__global__ void k_zero(float* __restrict__ p, long long n) {
    long long i = (long long)blockIdx.x * blockDim.x + threadIdx.x;
    long long stride = (long long)gridDim.x * blockDim.x;
    for (; i < n; i += stride) p[i] = 0.f;
}

// ---------------- W fp32 -> bf16 (once, 16384 elems) ----------------
__global__ void k_wcvt(const float* __restrict__ w, unsigned short* __restrict__ wb) {
    int i = blockIdx.x * 256 + threadIdx.x;
    if (i < 128 * 128) wb[i] = f2bf(w[i]);
}

// ------- h = x @ W^T via MFMA; h2 bf16; fused a_src/a_dst -------
__global__ __launch_bounds__(256) void k_lin(const float* __restrict__ x,
                                             const unsigned short* __restrict__ wb,
                                             const float* __restrict__ att_s,
                                             const float* __restrict__ att_d,
                                             unsigned short* __restrict__ h2,
                                             float* __restrict__ asrc,
                                             float* __restrict__ adst, int N) {
    const int t = threadIdx.x;
    const int lane = t & 63;
    const int wid = t >> 6;
    const int row0 = (blockIdx.x * 4 + wid) * 16;
    const int rlo = lane & 15;       // A-row / B-col / C-col offset
    const int khi = lane >> 4;       // k-chunk / C-row-group

    int arow = row0 + rlo; if (arow >= N) arow = N - 1;   // clamp (stores guarded)
    const float* xrow = x + (long long)arow * 128;
    bf16x8 afrag[4];
#pragma unroll
    for (int ks = 0; ks < 4; ++ks) {
        int k0 = ks * 32 + khi * 8;
        float4 xa = *(const float4*)(xrow + k0);
        float4 xb = *(const float4*)(xrow + k0 + 4);
        bf16x8 a;
        a[0] = (short)f2bf(xa.x); a[1] = (short)f2bf(xa.y);
        a[2] = (short)f2bf(xa.z); a[3] = (short)f2bf(xa.w);
        a[4] = (short)f2bf(xb.x); a[5] = (short)f2bf(xb.y);
        a[6] = (short)f2bf(xb.z); a[7] = (short)f2bf(xb.w);
        afrag[ks] = a;
    }

    float ps0[4] = {0.f,0.f,0.f,0.f}, pd0[4] = {0.f,0.f,0.f,0.f};
    float ps1[4] = {0.f,0.f,0.f,0.f}, pd1[4] = {0.f,0.f,0.f,0.f};

    for (int ct = 0; ct < 8; ++ct) {             // 8 col-tiles of 16
        const int col = ct * 16 + rlo;
        f32x4 acc = {0.f, 0.f, 0.f, 0.f};
#pragma unroll
        for (int ks = 0; ks < 4; ++ks) {
            bf16x8 b = *(const bf16x8*)(wb + (size_t)col * 128 + ks * 32 + khi * 8);
            acc = __builtin_amdgcn_mfma_f32_16x16x32_bf16(afrag[ks], b, acc, 0, 0, 0);
        }
        const float as = att_s[col], ad = att_d[col];
        const bool head0 = (ct < 4);             // wave-uniform
#pragma unroll
        for (int r = 0; r < 4; ++r) {
            int row = row0 + khi * 4 + r;
            if (row < N) h2[(long long)row * 128 + col] = f2bf(acc[r]);
            float v = acc[r];
            if (head0) { ps0[r] = fmaf(v, as, ps0[r]); pd0[r] = fmaf(v, ad, pd0[r]); }
            else       { ps1[r] = fmaf(v, as, ps1[r]); pd1[r] = fmaf(v, ad, pd1[r]); }
        }
    }

#pragma unroll
    for (int off = 1; off <= 8; off <<= 1) {
#pragma unroll
        for (int r = 0; r < 4; ++r) {
            ps0[r] += __shfl_xor(ps0[r], off);
            pd0[r] += __shfl_xor(pd0[r], off);
            ps1[r] += __shfl_xor(ps1[r], off);
            pd1[r] += __shfl_xor(pd1[r], off);
        }
    }
    if (rlo == 0) {
#pragma unroll
        for (int r = 0; r < 4; ++r) {
            int row = row0 + khi * 4 + r;
            if (row < N) {
                asrc[row * 2]     = ps0[r];
                asrc[row * 2 + 1] = ps1[r];
                adst[row * 2]     = pd0[r];
                adst[row * 2 + 1] = pd1[r];
            }
        }
    }
}

// ------- CSR build A: bucket histogram (one global atomic per block*bucket) ----
__global__ __launch_bounds__(256) void k_b0(const int* __restrict__ ei, int E,
                                            int* __restrict__ bcnt, int NB) {
    __shared__ int cnt[1024];
    int t = threadIdx.x;
    for (int i = t; i < 1024; i += 256) cnt[i] = 0;
    __syncthreads();
    int base = blockIdx.x * BIN_TILE;
    int end = min(base + BIN_TILE, E);
    for (int i = base + t; i < end; i += 256)
        atomicAdd(&cnt[ei[E + i] >> BKT_SHIFT], 1);
    __syncthreads();
    for (int b = t; b < NB; b += 256)
        if (cnt[b]) atomicAdd(&bcnt[b], cnt[b]);
}

// ------- CSR build B: scan bucket counts -> bases & cursors (1 block) ----------
__global__ __launch_bounds__(1024) void k_bscan(const int* __restrict__ bcnt,
                                                int* __restrict__ bbase,
                                                int* __restrict__ bcur, int NB, int E) {
    __shared__ int part[1024];
    int t = threadIdx.x;
    int v = (t < NB) ? bcnt[t] : 0;
    part[t] = v;
    __syncthreads();
    for (int off = 1; off < 1024; off <<= 1) {
        int u = (t >= off) ? part[t - off] : 0;
        __syncthreads();
        part[t] += u;
        __syncthreads();
    }
    if (t < NB) {
        int ex = part[t] - v;
        bbase[t] = ex;
        bcur[t] = ex;
    }
    if (t == 0) bbase[NB] = E;
}

// ------- CSR build C: bin edges into bucket runs (packed dl<<24|src) -----------
__global__ __launch_bounds__(256) void k_bin(const int* __restrict__ ei, int E,
                                             int* __restrict__ bcur,
                                             unsigned int* __restrict__ stage, int NB) {
    __shared__ int cnt[1024];
    __shared__ int gbase[1024];
    int t = threadIdx.x;
    for (int i = t; i < 1024; i += 256) cnt[i] = 0;
    __syncthreads();
    int base = blockIdx.x * BIN_TILE;
    int end = min(base + BIN_TILE, E);
    for (int i = base + t; i < end; i += 256)
        atomicAdd(&cnt[ei[E + i] >> BKT_SHIFT], 1);
    __syncthreads();
    for (int b = t; b < NB; b += 256) {
        int c = cnt[b];
        gbase[b] = c ? atomicAdd(&bcur[b], c) : 0;
    }
    __syncthreads();
    for (int i = t; i < 1024; i += 256) cnt[i] = 0;
    __syncthreads();
    for (int i = base + t; i < end; i += 256) {
        int s = ei[i];
        int d = ei[E + i];
        int b = d >> BKT_SHIFT;
        int off = atomicAdd(&cnt[b], 1);
        stage[gbase[b] + off] = ((unsigned int)(d & BKT_MASK) << 24) | (unsigned int)s;
    }
}

// ------- CSR build D: per-bucket counting sort; emits rowptr AND csr -----------
__global__ __launch_bounds__(256) void k_bsort(const int* __restrict__ bbase,
                                               const unsigned int* __restrict__ stage,
                                               int* __restrict__ rowptr,
                                               int* __restrict__ csr, int N, int E) {
    __shared__ int hist[256];
    __shared__ int sc[256];
    __shared__ int rp[256];
    __shared__ int lc[256];
    __shared__ int lout[BKT_CAP];
    int b = blockIdx.x;
    int node0 = b << BKT_SHIFT;
    int nloc = min(256, N - node0);
    int t = threadIdx.x;
    int bb = bbase[b], be = bbase[b + 1];
    hist[t] = 0; lc[t] = 0;
    __syncthreads();
    for (int i = bb + t; i < be; i += 256)
        atomicAdd(&hist[stage[i] >> 24], 1);
    __syncthreads();
    sc[t] = hist[t];
    __syncthreads();
    for (int off = 1; off < 256; off <<= 1) {
        int u = (t >= off) ? sc[t - off] : 0;
        __syncthreads();
        sc[t] += u;
        __syncthreads();
    }
    int rpg = bb + sc[t] - hist[t];
    rp[t] = rpg;
    if (t < nloc) rowptr[node0 + t] = rpg;
    if (b == 0 && t == 0) rowptr[N] = E;
    __syncthreads();
    for (int i = bb + t; i < be; i += 256) {
        unsigned int wrec = stage[i];
        int dl = (int)(wrec >> 24);
        int src = (int)(wrec & 0x00FFFFFFu);
        int pos = rp[dl] + atomicAdd(&lc[dl], 1);
        int rel = pos - bb;
        if (rel < BKT_CAP) lout[rel] = src;
        else csr[pos] = src;
    }
    __syncthreads();
    int cntb = be - bb; if (cntb > BKT_CAP) cntb = BKT_CAP;
    for (int i = t; i < cntb; i += 256) csr[bb + i] = lout[i];
}

// ------- aggregation: wave per dst; 4x16-lane groups; dwordx4 gathers (4 edges
//         per VMEM instr); LDS-staged per-edge weights; fused graph-pool -------
__global__ __launch_bounds__(256) void k_agg(const int* __restrict__ rowptr,
                                             const int* __restrict__ csr_src,
                                             const unsigned short* __restrict__ h2,
                                             const float* __restrict__ asrc,
                                             const float* __restrict__ adst,
                                             const float* __restrict__ bias,
                                             const int* __restrict__ batch,
                                             float* __restrict__ pooled, int N) {
    __shared__ int    lds_s[4][64];
    __shared__ float2 lds_u[4][64];
    const int wid  = threadIdx.x >> 6;
    const int lane = threadIdx.x & 63;
    const int q    = lane >> 4;      // edge subgroup (edge 4k+q)
    const int c    = lane & 15;      // channel quad: channels c*8..c*8+7
    int n = __builtin_amdgcn_readfirstlane(blockIdx.x * 4 + wid);
    if (n >= N) return;

    float2 adn = *(const float2*)(adst + (size_t)n * 2);
    float2 asn = *(const float2*)(asrc + (size_t)n * 2);
    float e0 = asn.x + adn.x; e0 = e0 > 0.f ? e0 : 0.2f * e0;
    float e1 = asn.y + adn.y; e1 = e1 > 0.f ? e1 : 0.2f * e1;
    float w0 = __expf(e0), w1 = __expf(e1);   // self-loop weights

    float acc[8];
#pragma unroll
    for (int j = 0; j < 8; ++j) acc[j] = 0.f;
    const bool headlo = (c < 8);     // channels <64 -> head0

    // self-loop: group 0 only (no cross-lane ops inside)
    if (q == 0) {
        uint4 v = *(const uint4*)(h2 + (size_t)n * 128 + c * 8);
        float wh = headlo ? w0 : w1;
        unsigned int vw[4] = {v.x, v.y, v.z, v.w};
#pragma unroll
        for (int m = 0; m < 4; ++m) {
            acc[m * 2]     = fmaf(wh, bf2f((unsigned short)(vw[m] & 0xffff)), acc[m * 2]);
            acc[m * 2 + 1] = fmaf(wh, bf2f((unsigned short)(vw[m] >> 16)),    acc[m * 2 + 1]);
        }
    }

    float ps0 = 0.f, ps1 = 0.f;
    const int beg = rowptr[n], end = rowptr[n + 1];

    for (int base = beg; base < end; base += 64) {
        int cnt = min(64, end - base);
        // stage 64 edges: weights computed once per edge, lane-parallel
        int sv = n;                              // pad: valid row, weight 0
        if (lane < cnt) sv = csr_src[base + lane];
        float2 a = *(const float2*)(asrc + (size_t)sv * 2);
        float f0 = a.x + adn.x; f0 = f0 > 0.f ? f0 : 0.2f * f0;
        float f1 = a.y + adn.y; f1 = f1 > 0.f ? f1 : 0.2f * f1;
        float u0 = (lane < cnt) ? __expf(f0) : 0.f;
        float u1 = (lane < cnt) ? __expf(f1) : 0.f;
        ps0 += u0; ps1 += u1;
        lds_s[wid][lane] = sv;
        lds_u[wid][lane] = make_float2(u0, u1);
        // wave-private LDS; same-wave RAW ordered via lgkmcnt (no barrier —
        // degree-dependent trip counts would deadlock __syncthreads)

        int kmax = (cnt + 3) >> 2;
#pragma unroll 4
        for (int k = 0; k < kmax; ++k) {
            int e = (k << 2) | q;
            int se = lds_s[wid][e];              // 4 addrs, 16-way broadcast
            float2 ue = lds_u[wid][e];
            float uh = headlo ? ue.x : ue.y;
            uint4 vv = *(const uint4*)(h2 + (size_t)se * 128 + c * 8);
            unsigned int vw[4] = {vv.x, vv.y, vv.z, vv.w};
#pragma unroll
            for (int m = 0; m < 4; ++m) {
                acc[m * 2]     = fmaf(uh, bf2f((unsigned short)(vw[m] & 0xffff)), acc[m * 2]);
                acc[m * 2 + 1] = fmaf(uh, bf2f((unsigned short)(vw[m] >> 16)),    acc[m * 2 + 1]);
            }
        }
    }

    // combine 4 edge-subgroups + softmax denominators (convergent, uniform)
#pragma unroll
    for (int j = 0; j < 8; ++j) {
        acc[j] += __shfl_xor(acc[j], 16);
        acc[j] += __shfl_xor(acc[j], 32);
    }
#pragma unroll
    for (int off = 32; off; off >>= 1) {
        ps0 += __shfl_xor(ps0, off);
        ps1 += __shfl_xor(ps1, off);
    }
    float s0 = ps0 + w0, s1 = ps1 + w1;

    if (q == 0) {
        float sdiv = headlo ? s0 : s1;
        int g = batch[n];
        float4 b0 = *(const float4*)(bias + c * 8);
        float4 b1 = *(const float4*)(bias + c * 8 + 4);
        float bb[8] = {b0.x, b0.y, b0.z, b0.w, b1.x, b1.y, b1.z, b1.w};
        float* pg = pooled + (size_t)g * 128 + c * 8;
#pragma unroll
        for (int j = 0; j < 8; ++j)
            atomicAdd(pg + j, acc[j] / sdiv + bb[j]);
    }
}

// ---------------- batchnorm stats over G graphs ----------------
__global__ __launch_bounds__(512) void k_bnstat(const float* __restrict__ pooled,
                                                const float* __restrict__ gamma,
                                                const float* __restrict__ beta,
                                                float* __restrict__ scale,
                                                float* __restrict__ shift, int G) {
    __shared__ float ls[512], lq[512];
    int t = threadIdx.x;
    int j = t & 127, q = t >> 7;
    int per = G >> 2;
    float sum = 0.f, sq = 0.f;
    for (int g = q * per; g < (q + 1) * per; ++g) {
        float v = pooled[g * 128 + j];
        sum += v; sq += v * v;
    }
    ls[t] = sum; lq[t] = sq;
    __syncthreads();
    if (t < 128) {
        sum = ls[t] + ls[t + 128] + ls[t + 256] + ls[t + 384];
        sq  = lq[t] + lq[t + 128] + lq[t + 256] + lq[t + 384];
        float mu = sum / (float)G;
        float var = sq / (float)G - mu * mu;
        float sc = gamma[t] * rsqrtf(var + 1e-5f);
        scale[t] = sc;
        shift[t] = beta[t] - mu * sc;
    }
}

// ---------------- norm + FC (block per graph) ----------------
__global__ __launch_bounds__(128) void k_fc(const float* __restrict__ pooled,
                                            const float* __restrict__ scale,
                                            const float* __restrict__ shift,
                                            const float* __restrict__ fcw,
                                            const float* __restrict__ fcb,
                                            float* __restrict__ out, int LAT) {
    __shared__ float nrm[128];
    int g = blockIdx.x;
    int t = threadIdx.x;
    nrm[t] = pooled[g * 128 + t] * scale[t] + shift[t];
    __syncthreads();
    if (t < LAT) {
        float acc = fcb[t];
#pragma unroll 8
        for (int j = 0; j < 128; ++j)
            acc = fmaf(nrm[j], fcw[t * 128 + j], acc);
        out[g * LAT + t] = acc;
    }
}

extern "C" void kernel_launch(void* const* d_in, const int* in_sizes, int n_in,
                              void* d_out, int out_size, void* d_ws, size_t ws_size,
                              hipStream_t stream) {
    const float* x     = (const float*)d_in[0];
    const int*   ei    = (const int*)d_in[1];
    const int*   batch = (const int*)d_in[2];
    const float* lin_w = (const float*)d_in[4];
    const float* att_s = (const float*)d_in[5];
    const float* att_d = (const float*)d_in[6];
    const float* bias  = (const float*)d_in[7];
    const float* gamma = (const float*)d_in[8];
    const float* beta  = (const float*)d_in[9];
    const float* fcw   = (const float*)d_in[10];
    const float* fcb   = (const float*)d_in[11];
    float* out = (float*)d_out;

    const int N   = in_sizes[2];
    const int E   = in_sizes[1] / 2;
    const int LAT = in_sizes[11];
    const int G   = out_size / LAT;
    const int NB  = (N + 255) >> BKT_SHIFT;

    char* ws = (char*)d_ws;
    unsigned short* h2 = (unsigned short*)ws; ws += (size_t)N * 128 * 2;
    unsigned short* wb = (unsigned short*)ws; ws += (size_t)128 * 128 * 2;
    float* asrc   = (float*)ws; ws += (size_t)N * 2 * 4;
    float* adst   = (float*)ws; ws += (size_t)N * 2 * 4;
    // zeroed region: bcnt | pooled (contiguous words)
    int*   bcnt   = (int*)ws;   ws += (size_t)NB * 4;
    float* pooled = (float*)ws; ws += (size_t)G * 128 * 4;
    float* scale  = (float*)ws; ws += 128 * 4;
    float* shift  = (float*)ws; ws += 128 * 4;
    int*   bbase  = (int*)ws;   ws += (size_t)(NB + 1) * 4;
    int*   bcur   = (int*)ws;   ws += (size_t)NB * 4;
    int*   rowptr = (int*)ws;   ws += (size_t)(N + 1) * 4;
    unsigned int* stage = (unsigned int*)ws; ws += (size_t)E * 4;
    int*   csr    = (int*)ws;   ws += (size_t)E * 4;

    long long nzero = (long long)NB + (long long)G * 128;
    k_zero<<<256, 256, 0, stream>>>((float*)bcnt, nzero);
    k_wcvt<<<64, 256, 0, stream>>>(lin_w, wb);

    k_lin<<<(N + 63) / 64, 256, 0, stream>>>(x, wb, att_s, att_d, h2, asrc, adst, N);
    int nbin = (E + BIN_TILE - 1) / BIN_TILE;
    k_b0<<<nbin, 256, 0, stream>>>(ei, E, bcnt, NB);
    k_bscan<<<1, 1024, 0, stream>>>(bcnt, bbase, bcur, NB, E);
    k_bin<<<nbin, 256, 0, stream>>>(ei, E, bcur, stage, NB);
    k_bsort<<<NB, 256, 0, stream>>>(bbase, stage, rowptr, csr, N, E);
    k_agg<<<(N + 3) / 4, 256, 0, stream>>>(rowptr, csr, h2, asrc, adst, bias, batch, pooled, N);
    k_bnstat<<<1, 512, 0, stream>>>(pooled, gamma, beta, scale, shift, G);
    k_fc<<<G, 128, 0, stream>>>(pooled, scale, shift, fcw, fcb, out, LAT);
}

// Round 11
// 247.010 us; speedup vs baseline: 1.5342x; 1.5342x over previous
//
#include <hip/hip_runtime.h>
#include <hip/hip_bf16.h>

// GAT. h = x@W^T via bf16 MFMA (16x16x32), no LDS; att coeffs fused into
// k_lin epilogue. CSR by dst via 2-level bucketed counting sort. k_agg:
// wave per dst, dword-per-lane channels; src ids via uniform s_load;
// edge weights: 1 exp/lane (half-wave per head) + 1 bpermute broadcast;
// wave-wide consecutive-address pooled atomics (line-friendly). BN; FC.
// H=2 x C=64.  Softmax max-shift skipped (|e| small, exp safe in fp32).
// All __shfl ops run with full exec (convergent) — never in divergent branches.

#define BKT_SHIFT 8              // 256 nodes per bucket
#define BKT_MASK  255
#define BKT_CAP   14336          // LDS staging records in k_bsort (56 KB)
#define BIN_TILE  4096           // edges per block in k_b0/k_bin

typedef __attribute__((ext_vector_type(8))) short bf16x8;
typedef __attribute__((ext_vector_type(4))) float f32x4;

static __device__ __forceinline__ float bf2f(unsigned short u) {
    union { unsigned int i; float f; } c; c.i = ((unsigned int)u) << 16; return c.f;
}
static __device__ __forceinline__ unsigned short f2bf(float f) {
    unsigned int b = __builtin_bit_cast(unsigned int, f);
    return (unsigned short)((b >> 16) + ((b >> 15) & 1));
}

// ---------------- zero fill ----------------
__global__ void k_zero(float* __restrict__ p, long long n) {
    long long i = (long long)blockIdx.x * blockDim.x + threadIdx.x;
    long long stride = (long long)gridDim.x * blockDim.x;
    for (; i < n; i += stride) p[i] = 0.f;
}

// ---------------- W fp32 -> bf16 (once, 16384 elems) ----------------
__global__ void k_wcvt(const float* __restrict__ w, unsigned short* __restrict__ wb) {
    int i = blockIdx.x * 256 + threadIdx.x;
    if (i < 128 * 128) wb[i] = f2bf(w[i]);
}

// ------- h = x @ W^T via MFMA; h2 bf16; fused a_src/a_dst -------
__global__ __launch_bounds__(256) void k_lin(const float* __restrict__ x,
                                             const unsigned short* __restrict__ wb,
                                             const float* __restrict__ att_s,
                                             const float* __restrict__ att_d,
                                             unsigned short* __restrict__ h2,
                                             float* __restrict__ asrc,
                                             float* __restrict__ adst, int N) {
    const int t = threadIdx.x;
    const int lane = t & 63;
    const int wid = t >> 6;
    const int row0 = (blockIdx.x * 4 + wid) * 16;
    const int rlo = lane & 15;       // A-row / B-col / C-col offset
    const int khi = lane >> 4;       // k-chunk / C-row-group

    int arow = row0 + rlo; if (arow >= N) arow = N - 1;   // clamp (stores guarded)
    const float* xrow = x + (long long)arow * 128;
    bf16x8 afrag[4];
#pragma unroll
    for (int ks = 0; ks < 4; ++ks) {
        int k0 = ks * 32 + khi * 8;
        float4 xa = *(const float4*)(xrow + k0);
        float4 xb = *(const float4*)(xrow + k0 + 4);
        bf16x8 a;
        a[0] = (short)f2bf(xa.x); a[1] = (short)f2bf(xa.y);
        a[2] = (short)f2bf(xa.z); a[3] = (short)f2bf(xa.w);
        a[4] = (short)f2bf(xb.x); a[5] = (short)f2bf(xb.y);
        a[6] = (short)f2bf(xb.z); a[7] = (short)f2bf(xb.w);
        afrag[ks] = a;
    }

    float ps0[4] = {0.f,0.f,0.f,0.f}, pd0[4] = {0.f,0.f,0.f,0.f};
    float ps1[4] = {0.f,0.f,0.f,0.f}, pd1[4] = {0.f,0.f,0.f,0.f};

    for (int ct = 0; ct < 8; ++ct) {             // 8 col-tiles of 16
        const int col = ct * 16 + rlo;
        f32x4 acc = {0.f, 0.f, 0.f, 0.f};
#pragma unroll
        for (int ks = 0; ks < 4; ++ks) {
            bf16x8 b = *(const bf16x8*)(wb + (size_t)col * 128 + ks * 32 + khi * 8);
            acc = __builtin_amdgcn_mfma_f32_16x16x32_bf16(afrag[ks], b, acc, 0, 0, 0);
        }
        const float as = att_s[col], ad = att_d[col];
        const bool head0 = (ct < 4);             // wave-uniform
#pragma unroll
        for (int r = 0; r < 4; ++r) {
            int row = row0 + khi * 4 + r;
            if (row < N) h2[(long long)row * 128 + col] = f2bf(acc[r]);
            float v = acc[r];
            if (head0) { ps0[r] = fmaf(v, as, ps0[r]); pd0[r] = fmaf(v, ad, pd0[r]); }
            else       { ps1[r] = fmaf(v, as, ps1[r]); pd1[r] = fmaf(v, ad, pd1[r]); }
        }
    }

#pragma unroll
    for (int off = 1; off <= 8; off <<= 1) {
#pragma unroll
        for (int r = 0; r < 4; ++r) {
            ps0[r] += __shfl_xor(ps0[r], off);
            pd0[r] += __shfl_xor(pd0[r], off);
            ps1[r] += __shfl_xor(ps1[r], off);
            pd1[r] += __shfl_xor(pd1[r], off);
        }
    }
    if (rlo == 0) {
#pragma unroll
        for (int r = 0; r < 4; ++r) {
            int row = row0 + khi * 4 + r;
            if (row < N) {
                asrc[row * 2]     = ps0[r];
                asrc[row * 2 + 1] = ps1[r];
                adst[row * 2]     = pd0[r];
                adst[row * 2 + 1] = pd1[r];
            }
        }
    }
}

// ------- CSR build A: bucket histogram (one global atomic per block*bucket) ----
__global__ __launch_bounds__(256) void k_b0(const int* __restrict__ ei, int E,
                                            int* __restrict__ bcnt, int NB) {
    __shared__ int cnt[1024];
    int t = threadIdx.x;
    for (int i = t; i < 1024; i += 256) cnt[i] = 0;
    __syncthreads();
    int base = blockIdx.x * BIN_TILE;
    int end = min(base + BIN_TILE, E);
    for (int i = base + t; i < end; i += 256)
        atomicAdd(&cnt[ei[E + i] >> BKT_SHIFT], 1);
    __syncthreads();
    for (int b = t; b < NB; b += 256)
        if (cnt[b]) atomicAdd(&bcnt[b], cnt[b]);
}

// ------- CSR build B: scan bucket counts -> bases & cursors (1 block) ----------
__global__ __launch_bounds__(1024) void k_bscan(const int* __restrict__ bcnt,
                                                int* __restrict__ bbase,
                                                int* __restrict__ bcur, int NB, int E) {
    __shared__ int part[1024];
    int t = threadIdx.x;
    int v = (t < NB) ? bcnt[t] : 0;
    part[t] = v;
    __syncthreads();
    for (int off = 1; off < 1024; off <<= 1) {
        int u = (t >= off) ? part[t - off] : 0;
        __syncthreads();
        part[t] += u;
        __syncthreads();
    }
    if (t < NB) {
        int ex = part[t] - v;
        bbase[t] = ex;
        bcur[t] = ex;
    }
    if (t == 0) bbase[NB] = E;
}

// ------- CSR build C: bin edges into bucket runs (packed dl<<24|src) -----------
__global__ __launch_bounds__(256) void k_bin(const int* __restrict__ ei, int E,
                                             int* __restrict__ bcur,
                                             unsigned int* __restrict__ stage, int NB) {
    __shared__ int cnt[1024];
    __shared__ int gbase[1024];
    int t = threadIdx.x;
    for (int i = t; i < 1024; i += 256) cnt[i] = 0;
    __syncthreads();
    int base = blockIdx.x * BIN_TILE;
    int end = min(base + BIN_TILE, E);
    for (int i = base + t; i < end; i += 256)
        atomicAdd(&cnt[ei[E + i] >> BKT_SHIFT], 1);
    __syncthreads();
    for (int b = t; b < NB; b += 256) {
        int c = cnt[b];
        gbase[b] = c ? atomicAdd(&bcur[b], c) : 0;
    }
    __syncthreads();
    for (int i = t; i < 1024; i += 256) cnt[i] = 0;
    __syncthreads();
    for (int i = base + t; i < end; i += 256) {
        int s = ei[i];
        int d = ei[E + i];
        int b = d >> BKT_SHIFT;
        int off = atomicAdd(&cnt[b], 1);
        stage[gbase[b] + off] = ((unsigned int)(d & BKT_MASK) << 24) | (unsigned int)s;
    }
}

// ------- CSR build D: per-bucket counting sort; emits rowptr AND csr -----------
__global__ __launch_bounds__(256) void k_bsort(const int* __restrict__ bbase,
                                               const unsigned int* __restrict__ stage,
                                               int* __restrict__ rowptr,
                                               int* __restrict__ csr, int N, int E) {
    __shared__ int hist[256];
    __shared__ int sc[256];
    __shared__ int rp[256];
    __shared__ int lc[256];
    __shared__ int lout[BKT_CAP];
    int b = blockIdx.x;
    int node0 = b << BKT_SHIFT;
    int nloc = min(256, N - node0);
    int t = threadIdx.x;
    int bb = bbase[b], be = bbase[b + 1];
    hist[t] = 0; lc[t] = 0;
    __syncthreads();
    for (int i = bb + t; i < be; i += 256)
        atomicAdd(&hist[stage[i] >> 24], 1);
    __syncthreads();
    sc[t] = hist[t];
    __syncthreads();
    for (int off = 1; off < 256; off <<= 1) {
        int u = (t >= off) ? sc[t - off] : 0;
        __syncthreads();
        sc[t] += u;
        __syncthreads();
    }
    int rpg = bb + sc[t] - hist[t];
    rp[t] = rpg;
    if (t < nloc) rowptr[node0 + t] = rpg;
    if (b == 0 && t == 0) rowptr[N] = E;
    __syncthreads();
    for (int i = bb + t; i < be; i += 256) {
        unsigned int wrec = stage[i];
        int dl = (int)(wrec >> 24);
        int src = (int)(wrec & 0x00FFFFFFu);
        int pos = rp[dl] + atomicAdd(&lc[dl], 1);
        int rel = pos - bb;
        if (rel < BKT_CAP) lout[rel] = src;
        else csr[pos] = src;
    }
    __syncthreads();
    int cntb = be - bb; if (cntb > BKT_CAP) cntb = BKT_CAP;
    for (int i = t; i < cntb; i += 256) csr[bb + i] = lout[i];
}

// ------- aggregation: wave per dst; 32-edge chunks; half-wave-per-head exp
//         (1 exp/lane); src via uniform s_load; 1 bpermute/edge for weight;
//         wave-wide consecutive pooled atomics -------
__global__ __launch_bounds__(256) void k_agg(const int* __restrict__ rowptr,
                                             const int* __restrict__ csr_src,
                                             const unsigned short* __restrict__ h2,
                                             const float* __restrict__ asrc,
                                             const float* __restrict__ adst,
                                             const float* __restrict__ bias,
                                             const int* __restrict__ batch,
                                             float* __restrict__ pooled, int N) {
    int n = __builtin_amdgcn_readfirstlane(blockIdx.x * 4 + (threadIdx.x >> 6));
    int lane = threadIdx.x & 63;
    if (n >= N) return;
    const bool lo = (lane < 32);
    const int el = lane & 31;        // edge slot within chunk
    const int hsel = lo ? 0 : 32;    // bpermute source offset for weight

    float2 adn = *(const float2*)(adst + (size_t)n * 2);
    float2 asn = *(const float2*)(asrc + (size_t)n * 2);
    float e0 = asn.x + adn.x; e0 = e0 > 0.f ? e0 : 0.2f * e0;
    float e1 = asn.y + adn.y; e1 = e1 > 0.f ? e1 : 0.2f * e1;
    float w0 = __expf(e0), w1 = __expf(e1);   // self-loop weights

    // self-loop: lane covers channels 2*lane, 2*lane+1
    unsigned int v = *(const unsigned int*)(h2 + (long long)n * 128 + lane * 2);
    float wsel = lo ? w0 : w1;
    float accX = wsel * bf2f((unsigned short)(v & 0xffff));
    float accY = wsel * bf2f((unsigned short)(v >> 16));
    float ps = 0.f;                  // low lanes: head0 partials; high: head1

    const float adh = lo ? adn.x : adn.y;
    const int beg = rowptr[n], end = rowptr[n + 1];

    for (int base = beg; base < end; base += 32) {
        int cnt = min(32, end - base);
        // per-lane edge weight: lane el<cnt owns edge el of this chunk,
        // low half computes head0 exp, high half head1 exp (1 exp/lane)
        int sv = n;
        if (el < cnt) sv = csr_src[base + el];           // coalesced (both halves same 128B)
        float av = asrc[(size_t)sv * 2 + (lo ? 0 : 1)];  // 4B gather
        float f = av + adh; f = f > 0.f ? f : 0.2f * f;
        float usel = (el < cnt) ? __expf(f) : 0.f;
        ps += usel;

#pragma unroll 4
        for (int e = 0; e < cnt; ++e) {
            int se = csr_src[base + e];                  // uniform -> s_load
            float uu = __shfl(usel, e + hsel);           // 1 bpermute (convergent)
            unsigned int vv = *(const unsigned int*)(h2 + (long long)se * 128 + lane * 2);
            accX = fmaf(uu, bf2f((unsigned short)(vv & 0xffff)), accX);
            accY = fmaf(uu, bf2f((unsigned short)(vv >> 16)),    accY);
        }
    }

    // reduce softmax denominator within each 32-lane half (xor<32 stays in half)
#pragma unroll
    for (int off = 1; off <= 16; off <<= 1)
        ps += __shfl_xor(ps, off);
    float sdiv = ps + (lo ? w0 : w1);

    int j0 = lane * 2;
    float2 bv = *(const float2*)(bias + j0);
    float o0 = accX / sdiv + bv.x;
    float o1 = accY / sdiv + bv.y;
    int g = batch[n];
    atomicAdd(&pooled[g * 128 + j0], o0);
    atomicAdd(&pooled[g * 128 + j0 + 1], o1);
}

// ---------------- batchnorm stats over G graphs ----------------
__global__ __launch_bounds__(512) void k_bnstat(const float* __restrict__ pooled,
                                                const float* __restrict__ gamma,
                                                const float* __restrict__ beta,
                                                float* __restrict__ scale,
                                                float* __restrict__ shift, int G) {
    __shared__ float ls[512], lq[512];
    int t = threadIdx.x;
    int j = t & 127, q = t >> 7;
    int per = G >> 2;
    float sum = 0.f, sq = 0.f;
    for (int g = q * per; g < (q + 1) * per; ++g) {
        float v = pooled[g * 128 + j];
        sum += v; sq += v * v;
    }
    ls[t] = sum; lq[t] = sq;
    __syncthreads();
    if (t < 128) {
        sum = ls[t] + ls[t + 128] + ls[t + 256] + ls[t + 384];
        sq  = lq[t] + lq[t + 128] + lq[t + 256] + lq[t + 384];
        float mu = sum / (float)G;
        float var = sq / (float)G - mu * mu;
        float sc = gamma[t] * rsqrtf(var + 1e-5f);
        scale[t] = sc;
        shift[t] = beta[t] - mu * sc;
    }
}

// ---------------- norm + FC (block per graph) ----------------
__global__ __launch_bounds__(128) void k_fc(const float* __restrict__ pooled,
                                            const float* __restrict__ scale,
                                            const float* __restrict__ shift,
                                            const float* __restrict__ fcw,
                                            const float* __restrict__ fcb,
                                            float* __restrict__ out, int LAT) {
    __shared__ float nrm[128];
    int g = blockIdx.x;
    int t = threadIdx.x;
    nrm[t] = pooled[g * 128 + t] * scale[t] + shift[t];
    __syncthreads();
    if (t < LAT) {
        float acc = fcb[t];
#pragma unroll 8
        for (int j = 0; j < 128; ++j)
            acc = fmaf(nrm[j], fcw[t * 128 + j], acc);
        out[g * LAT + t] = acc;
    }
}

extern "C" void kernel_launch(void* const* d_in, const int* in_sizes, int n_in,
                              void* d_out, int out_size, void* d_ws, size_t ws_size,
                              hipStream_t stream) {
    const float* x     = (const float*)d_in[0];
    const int*   ei    = (const int*)d_in[1];
    const int*   batch = (const int*)d_in[2];
    const float* lin_w = (const float*)d_in[4];
    const float* att_s = (const float*)d_in[5];
    const float* att_d = (const float*)d_in[6];
    const float* bias  = (const float*)d_in[7];
    const float* gamma = (const float*)d_in[8];
    const float* beta  = (const float*)d_in[9];
    const float* fcw   = (const float*)d_in[10];
    const float* fcb   = (const float*)d_in[11];
    float* out = (float*)d_out;

    const int N   = in_sizes[2];
    const int E   = in_sizes[1] / 2;
    const int LAT = in_sizes[11];
    const int G   = out_size / LAT;
    const int NB  = (N + 255) >> BKT_SHIFT;

    char* ws = (char*)d_ws;
    unsigned short* h2 = (unsigned short*)ws; ws += (size_t)N * 128 * 2;
    unsigned short* wb = (unsigned short*)ws; ws += (size_t)128 * 128 * 2;
    float* asrc   = (float*)ws; ws += (size_t)N * 2 * 4;
    float* adst   = (float*)ws; ws += (size_t)N * 2 * 4;
    // zeroed region: bcnt | pooled (contiguous words)
    int*   bcnt   = (int*)ws;   ws += (size_t)NB * 4;
    float* pooled = (float*)ws; ws += (size_t)G * 128 * 4;
    float* scale  = (float*)ws; ws += 128 * 4;
    float* shift  = (float*)ws; ws += 128 * 4;
    int*   bbase  = (int*)ws;   ws += (size_t)(NB + 1) * 4;
    int*   bcur   = (int*)ws;   ws += (size_t)NB * 4;
    int*   rowptr = (int*)ws;   ws += (size_t)(N + 1) * 4;
    unsigned int* stage = (unsigned int*)ws; ws += (size_t)E * 4;
    int*   csr    = (int*)ws;   ws += (size_t)E * 4;

    long long nzero = (long long)NB + (long long)G * 128;
    k_zero<<<256, 256, 0, stream>>>((float*)bcnt, nzero);
    k_wcvt<<<64, 256, 0, stream>>>(lin_w, wb);

    k_lin<<<(N + 63) / 64, 256, 0, stream>>>(x, wb, att_s, att_d, h2, asrc, adst, N);
    int nbin = (E + BIN_TILE - 1) / BIN_TILE;
    k_b0<<<nbin, 256, 0, stream>>>(ei, E, bcnt, NB);
    k_bscan<<<1, 1024, 0, stream>>>(bcnt, bbase, bcur, NB, E);
    k_bin<<<nbin, 256, 0, stream>>>(ei, E, bcur, stage, NB);
    k_bsort<<<NB, 256, 0, stream>>>(bbase, stage, rowptr, csr, N, E);
    k_agg<<<(N + 3) / 4, 256, 0, stream>>>(rowptr, csr, h2, asrc, adst, bias, batch, pooled, N);
    k_bnstat<<<1, 512, 0, stream>>>(pooled, gamma, beta, scale, shift, G);
    k_fc<<<G, 128, 0, stream>>>(pooled, scale, shift, fcw, fcb, out, LAT);
}

// Round 12
// 223.310 us; speedup vs baseline: 1.6970x; 1.1061x over previous
//
#include <hip/hip_runtime.h>
#include <hip/hip_bf16.h>

// GAT. h = x@W^T via bf16 MFMA (16x16x32), no LDS; att coeffs fused into
// k_lin epilogue. CSR by dst via 2-level bucketed counting sort. k_agg:
// HALF-WAVE per dst node (2 nodes/wave): lane owns 4 channels (uint2 of the
// 256B bf16 row); per step 3 bpermutes + 1 VMEM serve 2 edges (1.5 DS/edge);
// 1 exp-pair per lane per owned edge; epilogue register-transpose so pooled
// atomics hit consecutive dwords (8 line-RMWs/node). BN; FC 128->32.
// H=2 x C=64.  Softmax max-shift skipped (|e| small, exp safe in fp32).
// All __shfl sources stay within the active half (convergent-safe).
// NOTE: never mix s_load results with DS ops in a dependent loop (shared
// lgkmcnt, out-of-order completion -> forced full drains; R11 lesson).

#define BKT_SHIFT 8              // 256 nodes per bucket
#define BKT_MASK  255
#define BKT_CAP   14336          // LDS staging records in k_bsort (56 KB)
#define BIN_TILE  4096           // edges per block in k_b0/k_bin

typedef __attribute__((ext_vector_type(8))) short bf16x8;
typedef __attribute__((ext_vector_type(4))) float f32x4;

static __device__ __forceinline__ float bf2f(unsigned short u) {
    union { unsigned int i; float f; } c; c.i = ((unsigned int)u) << 16; return c.f;
}
static __device__ __forceinline__ float lo16(unsigned int u) {
    union { unsigned int i; float f; } c; c.i = u << 16; return c.f;
}
static __device__ __forceinline__ float hi16(unsigned int u) {
    union { unsigned int i; float f; } c; c.i = u & 0xffff0000u; return c.f;
}
static __device__ __forceinline__ unsigned short f2bf(float f) {
    unsigned int b = __builtin_bit_cast(unsigned int, f);
    return (unsigned short)((b >> 16) + ((b >> 15) & 1));
}

// ---------------- zero fill ----------------
__global__ void k_zero(float* __restrict__ p, long long n) {
    long long i = (long long)blockIdx.x * blockDim.x + threadIdx.x;
    long long stride = (long long)gridDim.x * blockDim.x;
    for (; i < n; i += stride) p[i] = 0.f;
}

// ---------------- W fp32 -> bf16 (once, 16384 elems) ----------------
__global__ void k_wcvt(const float* __restrict__ w, unsigned short* __restrict__ wb) {
    int i = blockIdx.x * 256 + threadIdx.x;
    if (i < 128 * 128) wb[i] = f2bf(w[i]);
}

// ------- h = x @ W^T via MFMA; h2 bf16; fused a_src/a_dst -------
__global__ __launch_bounds__(256) void k_lin(const float* __restrict__ x,
                                             const unsigned short* __restrict__ wb,
                                             const float* __restrict__ att_s,
                                             const float* __restrict__ att_d,
                                             unsigned short* __restrict__ h2,
                                             float* __restrict__ asrc,
                                             float* __restrict__ adst, int N) {
    const int t = threadIdx.x;
    const int lane = t & 63;
    const int wid = t >> 6;
    const int row0 = (blockIdx.x * 4 + wid) * 16;
    const int rlo = lane & 15;       // A-row / B-col / C-col offset
    const int khi = lane >> 4;       // k-chunk / C-row-group

    int arow = row0 + rlo; if (arow >= N) arow = N - 1;   // clamp (stores guarded)
    const float* xrow = x + (long long)arow * 128;
    bf16x8 afrag[4];
#pragma unroll
    for (int ks = 0; ks < 4; ++ks) {
        int k0 = ks * 32 + khi * 8;
        float4 xa = *(const float4*)(xrow + k0);
        float4 xb = *(const float4*)(xrow + k0 + 4);
        bf16x8 a;
        a[0] = (short)f2bf(xa.x); a[1] = (short)f2bf(xa.y);
        a[2] = (short)f2bf(xa.z); a[3] = (short)f2bf(xa.w);
        a[4] = (short)f2bf(xb.x); a[5] = (short)f2bf(xb.y);
        a[6] = (short)f2bf(xb.z); a[7] = (short)f2bf(xb.w);
        afrag[ks] = a;
    }

    float ps0[4] = {0.f,0.f,0.f,0.f}, pd0[4] = {0.f,0.f,0.f,0.f};
    float ps1[4] = {0.f,0.f,0.f,0.f}, pd1[4] = {0.f,0.f,0.f,0.f};

    for (int ct = 0; ct < 8; ++ct) {             // 8 col-tiles of 16
        const int col = ct * 16 + rlo;
        f32x4 acc = {0.f, 0.f, 0.f, 0.f};
#pragma unroll
        for (int ks = 0; ks < 4; ++ks) {
            bf16x8 b = *(const bf16x8*)(wb + (size_t)col * 128 + ks * 32 + khi * 8);
            acc = __builtin_amdgcn_mfma_f32_16x16x32_bf16(afrag[ks], b, acc, 0, 0, 0);
        }
        const float as = att_s[col], ad = att_d[col];
        const bool head0 = (ct < 4);             // wave-uniform
#pragma unroll
        for (int r = 0; r < 4; ++r) {
            int row = row0 + khi * 4 + r;
            if (row < N) h2[(long long)row * 128 + col] = f2bf(acc[r]);
            float v = acc[r];
            if (head0) { ps0[r] = fmaf(v, as, ps0[r]); pd0[r] = fmaf(v, ad, pd0[r]); }
            else       { ps1[r] = fmaf(v, as, ps1[r]); pd1[r] = fmaf(v, ad, pd1[r]); }
        }
    }

#pragma unroll
    for (int off = 1; off <= 8; off <<= 1) {
#pragma unroll
        for (int r = 0; r < 4; ++r) {
            ps0[r] += __shfl_xor(ps0[r], off);
            pd0[r] += __shfl_xor(pd0[r], off);
            ps1[r] += __shfl_xor(ps1[r], off);
            pd1[r] += __shfl_xor(pd1[r], off);
        }
    }
    if (rlo == 0) {
#pragma unroll
        for (int r = 0; r < 4; ++r) {
            int row = row0 + khi * 4 + r;
            if (row < N) {
                asrc[row * 2]     = ps0[r];
                asrc[row * 2 + 1] = ps1[r];
                adst[row * 2]     = pd0[r];
                adst[row * 2 + 1] = pd1[r];
            }
        }
    }
}

// ------- CSR build A: bucket histogram (one global atomic per block*bucket) ----
__global__ __launch_bounds__(256) void k_b0(const int* __restrict__ ei, int E,
                                            int* __restrict__ bcnt, int NB) {
    __shared__ int cnt[1024];
    int t = threadIdx.x;
    for (int i = t; i < 1024; i += 256) cnt[i] = 0;
    __syncthreads();
    int base = blockIdx.x * BIN_TILE;
    int end = min(base + BIN_TILE, E);
    for (int i = base + t; i < end; i += 256)
        atomicAdd(&cnt[ei[E + i] >> BKT_SHIFT], 1);
    __syncthreads();
    for (int b = t; b < NB; b += 256)
        if (cnt[b]) atomicAdd(&bcnt[b], cnt[b]);
}

// ------- CSR build B: scan bucket counts -> bases & cursors (1 block) ----------
__global__ __launch_bounds__(1024) void k_bscan(const int* __restrict__ bcnt,
                                                int* __restrict__ bbase,
                                                int* __restrict__ bcur, int NB, int E) {
    __shared__ int part[1024];
    int t = threadIdx.x;
    int v = (t < NB) ? bcnt[t] : 0;
    part[t] = v;
    __syncthreads();
    for (int off = 1; off < 1024; off <<= 1) {
        int u = (t >= off) ? part[t - off] : 0;
        __syncthreads();
        part[t] += u;
        __syncthreads();
    }
    if (t < NB) {
        int ex = part[t] - v;
        bbase[t] = ex;
        bcur[t] = ex;
    }
    if (t == 0) bbase[NB] = E;
}

// ------- CSR build C: bin edges into bucket runs (packed dl<<24|src) -----------
__global__ __launch_bounds__(256) void k_bin(const int* __restrict__ ei, int E,
                                             int* __restrict__ bcur,
                                             unsigned int* __restrict__ stage, int NB) {
    __shared__ int cnt[1024];
    __shared__ int gbase[1024];
    int t = threadIdx.x;
    for (int i = t; i < 1024; i += 256) cnt[i] = 0;
    __syncthreads();
    int base = blockIdx.x * BIN_TILE;
    int end = min(base + BIN_TILE, E);
    for (int i = base + t; i < end; i += 256)
        atomicAdd(&cnt[ei[E + i] >> BKT_SHIFT], 1);
    __syncthreads();
    for (int b = t; b < NB; b += 256) {
        int c = cnt[b];
        gbase[b] = c ? atomicAdd(&bcur[b], c) : 0;
    }
    __syncthreads();
    for (int i = t; i < 1024; i += 256) cnt[i] = 0;
    __syncthreads();
    for (int i = base + t; i < end; i += 256) {
        int s = ei[i];
        int d = ei[E + i];
        int b = d >> BKT_SHIFT;
        int off = atomicAdd(&cnt[b], 1);
        stage[gbase[b] + off] = ((unsigned int)(d & BKT_MASK) << 24) | (unsigned int)s;
    }
}

// ------- CSR build D: per-bucket counting sort; emits rowptr AND csr -----------
__global__ __launch_bounds__(256) void k_bsort(const int* __restrict__ bbase,
                                               const unsigned int* __restrict__ stage,
                                               int* __restrict__ rowptr,
                                               int* __restrict__ csr, int N, int E) {
    __shared__ int hist[256];
    __shared__ int sc[256];
    __shared__ int rp[256];
    __shared__ int lc[256];
    __shared__ int lout[BKT_CAP];
    int b = blockIdx.x;
    int node0 = b << BKT_SHIFT;
    int nloc = min(256, N - node0);
    int t = threadIdx.x;
    int bb = bbase[b], be = bbase[b + 1];
    hist[t] = 0; lc[t] = 0;
    __syncthreads();
    for (int i = bb + t; i < be; i += 256)
        atomicAdd(&hist[stage[i] >> 24], 1);
    __syncthreads();
    sc[t] = hist[t];
    __syncthreads();
    for (int off = 1; off < 256; off <<= 1) {
        int u = (t >= off) ? sc[t - off] : 0;
        __syncthreads();
        sc[t] += u;
        __syncthreads();
    }
    int rpg = bb + sc[t] - hist[t];
    rp[t] = rpg;
    if (t < nloc) rowptr[node0 + t] = rpg;
    if (b == 0 && t == 0) rowptr[N] = E;
    __syncthreads();
    for (int i = bb + t; i < be; i += 256) {
        unsigned int wrec = stage[i];
        int dl = (int)(wrec >> 24);
        int src = (int)(wrec & 0x00FFFFFFu);
        int pos = rp[dl] + atomicAdd(&lc[dl], 1);
        int rel = pos - bb;
        if (rel < BKT_CAP) lout[rel] = src;
        else csr[pos] = src;
    }
    __syncthreads();
    int cntb = be - bb; if (cntb > BKT_CAP) cntb = BKT_CAP;
    for (int i = t; i < cntb; i += 256) csr[bb + i] = lout[i];
}

// ------- aggregation: half-wave per dst; lane owns 4 channels (uint2);
//         3 bpermutes + 1 VMEM per 2 edges; transpose epilogue;
//         consecutive-dword pooled atomics -------
__global__ __launch_bounds__(256) void k_agg(const int* __restrict__ rowptr,
                                             const int* __restrict__ csr_src,
                                             const unsigned short* __restrict__ h2,
                                             const float* __restrict__ asrc,
                                             const float* __restrict__ adst,
                                             const float* __restrict__ bias,
                                             const int* __restrict__ batch,
                                             float* __restrict__ pooled, int N) {
    const int lane  = threadIdx.x & 63;
    const int half  = lane >> 5;       // which node of the pair
    const int c     = lane & 31;       // channel quad: channels 4c..4c+3
    const int hbase = half << 5;       // shfl base for my half
    int n = blockIdx.x * 8 + ((threadIdx.x >> 6) << 1) + half;
    const bool nvalid = (n < N);
    const int nc = nvalid ? n : 0;

    float2 adn = *(const float2*)(adst + (size_t)nc * 2);
    float2 asn = *(const float2*)(asrc + (size_t)nc * 2);
    float e0 = asn.x + adn.x; e0 = e0 > 0.f ? e0 : 0.2f * e0;
    float e1 = asn.y + adn.y; e1 = e1 > 0.f ? e1 : 0.2f * e1;
    float w0 = __expf(e0), w1 = __expf(e1);   // self-loop weights

    // self-loop: channels 4c..4c+3 (head0 iff c<16)
    uint2 v = *(const uint2*)(h2 + (size_t)nc * 128 + c * 4);
    float wh = (c < 16) ? w0 : w1;
    float a0 = wh * lo16(v.x), a1 = wh * hi16(v.x);
    float a2 = wh * lo16(v.y), a3 = wh * hi16(v.y);
    float ps0 = 0.f, ps1 = 0.f;

    const int beg = rowptr[nc], end = rowptr[nc + 1];
    for (int base = beg; base < end; base += 32) {
        int cnt = min(32, end - base);   // uniform within half
        int sv = nc; float u0 = 0.f, u1 = 0.f;
        if (c < cnt) {
            sv = csr_src[base + c];                          // coalesced per half
            float2 a = *(const float2*)(asrc + (size_t)sv * 2);
            float f0 = a.x + adn.x; f0 = f0 > 0.f ? f0 : 0.2f * f0;
            float f1 = a.y + adn.y; f1 = f1 > 0.f ? f1 : 0.2f * f1;
            u0 = __expf(f0); u1 = __expf(f1);
        }
        ps0 += u0; ps1 += u1;

        int k = 0;
        for (; k + 4 <= cnt; k += 4) {
            int sA = __shfl(sv, hbase + k);
            int sB = __shfl(sv, hbase + k + 1);
            int sC = __shfl(sv, hbase + k + 2);
            int sD = __shfl(sv, hbase + k + 3);
            uint2 vA = *(const uint2*)(h2 + (size_t)sA * 128 + c * 4);
            uint2 vB = *(const uint2*)(h2 + (size_t)sB * 128 + c * 4);
            uint2 vC = *(const uint2*)(h2 + (size_t)sC * 128 + c * 4);
            uint2 vD = *(const uint2*)(h2 + (size_t)sD * 128 + c * 4);
            float uA0 = __shfl(u0, hbase + k),     uA1 = __shfl(u1, hbase + k);
            float uB0 = __shfl(u0, hbase + k + 1), uB1 = __shfl(u1, hbase + k + 1);
            float uC0 = __shfl(u0, hbase + k + 2), uC1 = __shfl(u1, hbase + k + 2);
            float uD0 = __shfl(u0, hbase + k + 3), uD1 = __shfl(u1, hbase + k + 3);
            float uA = (c < 16) ? uA0 : uA1;
            float uB = (c < 16) ? uB0 : uB1;
            float uC = (c < 16) ? uC0 : uC1;
            float uD = (c < 16) ? uD0 : uD1;
            a0 = fmaf(uA, lo16(vA.x), a0); a1 = fmaf(uA, hi16(vA.x), a1);
            a2 = fmaf(uA, lo16(vA.y), a2); a3 = fmaf(uA, hi16(vA.y), a3);
            a0 = fmaf(uB, lo16(vB.x), a0); a1 = fmaf(uB, hi16(vB.x), a1);
            a2 = fmaf(uB, lo16(vB.y), a2); a3 = fmaf(uB, hi16(vB.y), a3);
            a0 = fmaf(uC, lo16(vC.x), a0); a1 = fmaf(uC, hi16(vC.x), a1);
            a2 = fmaf(uC, lo16(vC.y), a2); a3 = fmaf(uC, hi16(vC.y), a3);
            a0 = fmaf(uD, lo16(vD.x), a0); a1 = fmaf(uD, hi16(vD.x), a1);
            a2 = fmaf(uD, lo16(vD.y), a2); a3 = fmaf(uD, hi16(vD.y), a3);
        }
        for (; k < cnt; ++k) {
            int sA = __shfl(sv, hbase + k);
            uint2 vA = *(const uint2*)(h2 + (size_t)sA * 128 + c * 4);
            float uA0 = __shfl(u0, hbase + k), uA1 = __shfl(u1, hbase + k);
            float uA = (c < 16) ? uA0 : uA1;
            a0 = fmaf(uA, lo16(vA.x), a0); a1 = fmaf(uA, hi16(vA.x), a1);
            a2 = fmaf(uA, lo16(vA.y), a2); a3 = fmaf(uA, hi16(vA.y), a3);
        }
    }

    // softmax denominators: reduce within each 32-lane half (reconverged here)
#pragma unroll
    for (int off = 1; off <= 16; off <<= 1) {
        ps0 += __shfl_xor(ps0, off);
        ps1 += __shfl_xor(ps1, off);
    }
    float sdiv = (c < 16) ? (ps0 + w0) : (ps1 + w1);
    float r0 = a0 / sdiv, r1 = a1 / sdiv, r2 = a2 / sdiv, r3 = a3 / sdiv;

    // transpose within half: lane c gets channels {c, 32+c, 64+c, 96+c}
    // channel 32m+c lives on lane 8m+(c>>2), slot c&3
    float wacc[4];
    const int j = c & 3;
#pragma unroll
    for (int m = 0; m < 4; ++m) {
        int src = hbase + 8 * m + (c >> 2);
        float t0 = __shfl(r0, src);
        float t1 = __shfl(r1, src);
        float t2 = __shfl(r2, src);
        float t3 = __shfl(r3, src);
        wacc[m] = (j == 0) ? t0 : (j == 1) ? t1 : (j == 2) ? t2 : t3;
    }

    if (nvalid) {
        int g = batch[nc];
#pragma unroll
        for (int m = 0; m < 4; ++m)
            atomicAdd(&pooled[(size_t)g * 128 + 32 * m + c], wacc[m] + bias[32 * m + c]);
    }
}

// ---------------- batchnorm stats over G graphs ----------------
__global__ __launch_bounds__(512) void k_bnstat(const float* __restrict__ pooled,
                                                const float* __restrict__ gamma,
                                                const float* __restrict__ beta,
                                                float* __restrict__ scale,
                                                float* __restrict__ shift, int G) {
    __shared__ float ls[512], lq[512];
    int t = threadIdx.x;
    int j = t & 127, q = t >> 7;
    int per = G >> 2;
    float sum = 0.f, sq = 0.f;
    for (int g = q * per; g < (q + 1) * per; ++g) {
        float v = pooled[g * 128 + j];
        sum += v; sq += v * v;
    }
    ls[t] = sum; lq[t] = sq;
    __syncthreads();
    if (t < 128) {
        sum = ls[t] + ls[t + 128] + ls[t + 256] + ls[t + 384];
        sq  = lq[t] + lq[t + 128] + lq[t + 256] + lq[t + 384];
        float mu = sum / (float)G;
        float var = sq / (float)G - mu * mu;
        float sc = gamma[t] * rsqrtf(var + 1e-5f);
        scale[t] = sc;
        shift[t] = beta[t] - mu * sc;
    }
}

// ---------------- norm + FC (block per graph) ----------------
__global__ __launch_bounds__(128) void k_fc(const float* __restrict__ pooled,
                                            const float* __restrict__ scale,
                                            const float* __restrict__ shift,
                                            const float* __restrict__ fcw,
                                            const float* __restrict__ fcb,
                                            float* __restrict__ out, int LAT) {
    __shared__ float nrm[128];
    int g = blockIdx.x;
    int t = threadIdx.x;
    nrm[t] = pooled[g * 128 + t] * scale[t] + shift[t];
    __syncthreads();
    if (t < LAT) {
        float acc = fcb[t];
#pragma unroll 8
        for (int j = 0; j < 128; ++j)
            acc = fmaf(nrm[j], fcw[t * 128 + j], acc);
        out[g * LAT + t] = acc;
    }
}

extern "C" void kernel_launch(void* const* d_in, const int* in_sizes, int n_in,
                              void* d_out, int out_size, void* d_ws, size_t ws_size,
                              hipStream_t stream) {
    const float* x     = (const float*)d_in[0];
    const int*   ei    = (const int*)d_in[1];
    const int*   batch = (const int*)d_in[2];
    const float* lin_w = (const float*)d_in[4];
    const float* att_s = (const float*)d_in[5];
    const float* att_d = (const float*)d_in[6];
    const float* bias  = (const float*)d_in[7];
    const float* gamma = (const float*)d_in[8];
    const float* beta  = (const float*)d_in[9];
    const float* fcw   = (const float*)d_in[10];
    const float* fcb   = (const float*)d_in[11];
    float* out = (float*)d_out;

    const int N   = in_sizes[2];
    const int E   = in_sizes[1] / 2;
    const int LAT = in_sizes[11];
    const int G   = out_size / LAT;
    const int NB  = (N + 255) >> BKT_SHIFT;

    char* ws = (char*)d_ws;
    unsigned short* h2 = (unsigned short*)ws; ws += (size_t)N * 128 * 2;
    unsigned short* wb = (unsigned short*)ws; ws += (size_t)128 * 128 * 2;
    float* asrc   = (float*)ws; ws += (size_t)N * 2 * 4;
    float* adst   = (float*)ws; ws += (size_t)N * 2 * 4;
    // zeroed region: bcnt | pooled (contiguous words)
    int*   bcnt   = (int*)ws;   ws += (size_t)NB * 4;
    float* pooled = (float*)ws; ws += (size_t)G * 128 * 4;
    float* scale  = (float*)ws; ws += 128 * 4;
    float* shift  = (float*)ws; ws += 128 * 4;
    int*   bbase  = (int*)ws;   ws += (size_t)(NB + 1) * 4;
    int*   bcur   = (int*)ws;   ws += (size_t)NB * 4;
    int*   rowptr = (int*)ws;   ws += (size_t)(N + 1) * 4;
    unsigned int* stage = (unsigned int*)ws; ws += (size_t)E * 4;
    int*   csr    = (int*)ws;   ws += (size_t)E * 4;

    long long nzero = (long long)NB + (long long)G * 128;
    k_zero<<<256, 256, 0, stream>>>((float*)bcnt, nzero);
    k_wcvt<<<64, 256, 0, stream>>>(lin_w, wb);

    k_lin<<<(N + 63) / 64, 256, 0, stream>>>(x, wb, att_s, att_d, h2, asrc, adst, N);
    int nbin = (E + BIN_TILE - 1) / BIN_TILE;
    k_b0<<<nbin, 256, 0, stream>>>(ei, E, bcnt, NB);
    k_bscan<<<1, 1024, 0, stream>>>(bcnt, bbase, bcur, NB, E);
    k_bin<<<nbin, 256, 0, stream>>>(ei, E, bcur, stage, NB);
    k_bsort<<<NB, 256, 0, stream>>>(bbase, stage, rowptr, csr, N, E);
    k_agg<<<(N + 7) / 8, 256, 0, stream>>>(rowptr, csr, h2, asrc, adst, bias, batch, pooled, N);
    k_bnstat<<<1, 512, 0, stream>>>(pooled, gamma, beta, scale, shift, G);
    k_fc<<<G, 128, 0, stream>>>(pooled, scale, shift, fcw, fcb, out, LAT);
}

// Round 13
// 211.935 us; speedup vs baseline: 1.7881x; 1.0537x over previous
//
#include <hip/hip_runtime.h>
#include <hip/hip_bf16.h>

// GAT. h = x@W^T via bf16 MFMA (16x16x32); att coeffs fused in k_lin.
// CSR by dst via 2-level bucketed counting sort. k_agg: wave per dst,
// SCALARIZED broadcasts (v_readlane -> SGPR src id + weights; SALU address;
// coalesced 256B row gather; zero DS ops in hot loop; 8-deep unroll).
// Fused graph pooling (consecutive-dword atomics). BN; FC 128->32.
// H=2 x C=64.  Softmax max-shift skipped (|e| small, exp safe in fp32).
// Lessons: shfl under divergence = poison (R7); s_load in DS loops = lgkmcnt
// drains (R11); split-lane atomics = write amplification (R10).

#define BKT_SHIFT 8              // 256 nodes per bucket
#define BKT_MASK  255
#define BKT_CAP   14336          // LDS staging records in k_bsort (56 KB)
#define BIN_TILE  4096           // edges per block in k_b0/k_bin

typedef __attribute__((ext_vector_type(8))) short bf16x8;
typedef __attribute__((ext_vector_type(4))) float f32x4;

static __device__ __forceinline__ float lo16(unsigned int u) {
    union { unsigned int i; float f; } c; c.i = u << 16; return c.f;
}
static __device__ __forceinline__ float hi16(unsigned int u) {
    union { unsigned int i; float f; } c; c.i = u & 0xffff0000u; return c.f;
}
static __device__ __forceinline__ unsigned short f2bf(float f) {
    unsigned int b = __builtin_bit_cast(unsigned int, f);
    return (unsigned short)((b >> 16) + ((b >> 15) & 1));
}
static __device__ __forceinline__ float rlane_f(float x, int l) {
    return __builtin_bit_cast(float, __builtin_amdgcn_readlane(__builtin_bit_cast(int, x), l));
}

// ---------------- zero fill ----------------
__global__ void k_zero(float* __restrict__ p, long long n) {
    long long i = (long long)blockIdx.x * blockDim.x + threadIdx.x;
    long long stride = (long long)gridDim.x * blockDim.x;
    for (; i < n; i += stride) p[i] = 0.f;
}

// ---------------- W fp32 -> bf16 (once, 16384 elems) ----------------
__global__ void k_wcvt(const float* __restrict__ w, unsigned short* __restrict__ wb) {
    int i = blockIdx.x * 256 + threadIdx.x;
    if (i < 128 * 128) wb[i] = f2bf(w[i]);
}

// ------- h = x @ W^T via MFMA; h2 bf16; fused a_src/a_dst -------
__global__ __launch_bounds__(256) void k_lin(const float* __restrict__ x,
                                             const unsigned short* __restrict__ wb,
                                             const float* __restrict__ att_s,
                                             const float* __restrict__ att_d,
                                             unsigned short* __restrict__ h2,
                                             float* __restrict__ asrc,
                                             float* __restrict__ adst, int N) {
    const int t = threadIdx.x;
    const int lane = t & 63;
    const int wid = t >> 6;
    const int row0 = (blockIdx.x * 4 + wid) * 16;
    const int rlo = lane & 15;       // A-row / B-col / C-col offset
    const int khi = lane >> 4;       // k-chunk / C-row-group

    int arow = row0 + rlo; if (arow >= N) arow = N - 1;   // clamp (stores guarded)
    const float* xrow = x + (long long)arow * 128;
    bf16x8 afrag[4];
#pragma unroll
    for (int ks = 0; ks < 4; ++ks) {
        int k0 = ks * 32 + khi * 8;
        float4 xa = *(const float4*)(xrow + k0);
        float4 xb = *(const float4*)(xrow + k0 + 4);
        bf16x8 a;
        a[0] = (short)f2bf(xa.x); a[1] = (short)f2bf(xa.y);
        a[2] = (short)f2bf(xa.z); a[3] = (short)f2bf(xa.w);
        a[4] = (short)f2bf(xb.x); a[5] = (short)f2bf(xb.y);
        a[6] = (short)f2bf(xb.z); a[7] = (short)f2bf(xb.w);
        afrag[ks] = a;
    }

    float ps0[4] = {0.f,0.f,0.f,0.f}, pd0[4] = {0.f,0.f,0.f,0.f};
    float ps1[4] = {0.f,0.f,0.f,0.f}, pd1[4] = {0.f,0.f,0.f,0.f};

    for (int ct = 0; ct < 8; ++ct) {             // 8 col-tiles of 16
        const int col = ct * 16 + rlo;
        f32x4 acc = {0.f, 0.f, 0.f, 0.f};
#pragma unroll
        for (int ks = 0; ks < 4; ++ks) {
            bf16x8 b = *(const bf16x8*)(wb + (size_t)col * 128 + ks * 32 + khi * 8);
            acc = __builtin_amdgcn_mfma_f32_16x16x32_bf16(afrag[ks], b, acc, 0, 0, 0);
        }
        const float as = att_s[col], ad = att_d[col];
        const bool head0 = (ct < 4);             // wave-uniform
#pragma unroll
        for (int r = 0; r < 4; ++r) {
            int row = row0 + khi * 4 + r;
            if (row < N) h2[(long long)row * 128 + col] = f2bf(acc[r]);
            float v = acc[r];
            if (head0) { ps0[r] = fmaf(v, as, ps0[r]); pd0[r] = fmaf(v, ad, pd0[r]); }
            else       { ps1[r] = fmaf(v, as, ps1[r]); pd1[r] = fmaf(v, ad, pd1[r]); }
        }
    }

#pragma unroll
    for (int off = 1; off <= 8; off <<= 1) {
#pragma unroll
        for (int r = 0; r < 4; ++r) {
            ps0[r] += __shfl_xor(ps0[r], off);
            pd0[r] += __shfl_xor(pd0[r], off);
            ps1[r] += __shfl_xor(ps1[r], off);
            pd1[r] += __shfl_xor(pd1[r], off);
        }
    }
    if (rlo == 0) {
#pragma unroll
        for (int r = 0; r < 4; ++r) {
            int row = row0 + khi * 4 + r;
            if (row < N) {
                asrc[row * 2]     = ps0[r];
                asrc[row * 2 + 1] = ps1[r];
                adst[row * 2]     = pd0[r];
                adst[row * 2 + 1] = pd1[r];
            }
        }
    }
}

// ------- CSR build A: bucket histogram (one global atomic per block*bucket) ----
__global__ __launch_bounds__(256) void k_b0(const int* __restrict__ ei, int E,
                                            int* __restrict__ bcnt, int NB) {
    __shared__ int cnt[1024];
    int t = threadIdx.x;
    for (int i = t; i < 1024; i += 256) cnt[i] = 0;
    __syncthreads();
    int base = blockIdx.x * BIN_TILE;
    int end = min(base + BIN_TILE, E);
    for (int i = base + t; i < end; i += 256)
        atomicAdd(&cnt[ei[E + i] >> BKT_SHIFT], 1);
    __syncthreads();
    for (int b = t; b < NB; b += 256)
        if (cnt[b]) atomicAdd(&bcnt[b], cnt[b]);
}

// ------- CSR build B: scan bucket counts -> bases & cursors (1 block) ----------
__global__ __launch_bounds__(1024) void k_bscan(const int* __restrict__ bcnt,
                                                int* __restrict__ bbase,
                                                int* __restrict__ bcur, int NB, int E) {
    __shared__ int part[1024];
    int t = threadIdx.x;
    int v = (t < NB) ? bcnt[t] : 0;
    part[t] = v;
    __syncthreads();
    for (int off = 1; off < 1024; off <<= 1) {
        int u = (t >= off) ? part[t - off] : 0;
        __syncthreads();
        part[t] += u;
        __syncthreads();
    }
    if (t < NB) {
        int ex = part[t] - v;
        bbase[t] = ex;
        bcur[t] = ex;
    }
    if (t == 0) bbase[NB] = E;
}

// ------- CSR build C: bin edges into bucket runs (packed dl<<24|src) -----------
__global__ __launch_bounds__(256) void k_bin(const int* __restrict__ ei, int E,
                                             int* __restrict__ bcur,
                                             unsigned int* __restrict__ stage, int NB) {
    __shared__ int cnt[1024];
    __shared__ int gbase[1024];
    int t = threadIdx.x;
    for (int i = t; i < 1024; i += 256) cnt[i] = 0;
    __syncthreads();
    int base = blockIdx.x * BIN_TILE;
    int end = min(base + BIN_TILE, E);
    for (int i = base + t; i < end; i += 256)
        atomicAdd(&cnt[ei[E + i] >> BKT_SHIFT], 1);
    __syncthreads();
    for (int b = t; b < NB; b += 256) {
        int c = cnt[b];
        gbase[b] = c ? atomicAdd(&bcur[b], c) : 0;
    }
    __syncthreads();
    for (int i = t; i < 1024; i += 256) cnt[i] = 0;
    __syncthreads();
    for (int i = base + t; i < end; i += 256) {
        int s = ei[i];
        int d = ei[E + i];
        int b = d >> BKT_SHIFT;
        int off = atomicAdd(&cnt[b], 1);
        stage[gbase[b] + off] = ((unsigned int)(d & BKT_MASK) << 24) | (unsigned int)s;
    }
}

// ------- CSR build D: per-bucket counting sort; emits rowptr AND csr -----------
__global__ __launch_bounds__(256) void k_bsort(const int* __restrict__ bbase,
                                               const unsigned int* __restrict__ stage,
                                               int* __restrict__ rowptr,
                                               int* __restrict__ csr, int N, int E) {
    __shared__ int hist[256];
    __shared__ int sc[256];
    __shared__ int rp[256];
    __shared__ int lc[256];
    __shared__ int lout[BKT_CAP];
    int b = blockIdx.x;
    int node0 = b << BKT_SHIFT;
    int nloc = min(256, N - node0);
    int t = threadIdx.x;
    int bb = bbase[b], be = bbase[b + 1];
    hist[t] = 0; lc[t] = 0;
    __syncthreads();
    for (int i = bb + t; i < be; i += 256)
        atomicAdd(&hist[stage[i] >> 24], 1);
    __syncthreads();
    sc[t] = hist[t];
    __syncthreads();
    for (int off = 1; off < 256; off <<= 1) {
        int u = (t >= off) ? sc[t - off] : 0;
        __syncthreads();
        sc[t] += u;
        __syncthreads();
    }
    int rpg = bb + sc[t] - hist[t];
    rp[t] = rpg;
    if (t < nloc) rowptr[node0 + t] = rpg;
    if (b == 0 && t == 0) rowptr[N] = E;
    __syncthreads();
    for (int i = bb + t; i < be; i += 256) {
        unsigned int wrec = stage[i];
        int dl = (int)(wrec >> 24);
        int src = (int)(wrec & 0x00FFFFFFu);
        int pos = rp[dl] + atomicAdd(&lc[dl], 1);
        int rel = pos - bb;
        if (rel < BKT_CAP) lout[rel] = src;
        else csr[pos] = src;
    }
    __syncthreads();
    int cntb = be - bb; if (cntb > BKT_CAP) cntb = BKT_CAP;
    for (int i = t; i < cntb; i += 256) csr[bb + i] = lout[i];
}

// ------- aggregation: wave per dst; scalarized broadcasts (readlane/SALU);
//         coalesced 256B row gathers; zero DS in hot loop -------
__global__ __launch_bounds__(256) void k_agg(const int* __restrict__ rowptr,
                                             const int* __restrict__ csr_src,
                                             const unsigned short* __restrict__ h2,
                                             const float* __restrict__ asrc,
                                             const float* __restrict__ adst,
                                             const float* __restrict__ bias,
                                             const int* __restrict__ batch,
                                             float* __restrict__ pooled, int N) {
    int n = __builtin_amdgcn_readfirstlane(blockIdx.x * 4 + (threadIdx.x >> 6));
    const int lane = threadIdx.x & 63;
    if (n >= N) return;
    const bool lo = (lane < 32);
    const int el = lane & 31;        // owned edge slot within 32-edge chunk

    float2 adn = *(const float2*)(adst + (size_t)n * 2);
    float2 asn = *(const float2*)(asrc + (size_t)n * 2);
    float e0 = asn.x + adn.x; e0 = e0 > 0.f ? e0 : 0.2f * e0;
    float e1 = asn.y + adn.y; e1 = e1 > 0.f ? e1 : 0.2f * e1;
    float w0 = __expf(e0), w1 = __expf(e1);   // self-loop weights

    // self-loop: lane owns dword `lane` of the row = channels 2lane, 2lane+1
    unsigned int v = ((const unsigned int*)(h2 + (size_t)n * 128))[lane];
    float wh = lo ? w0 : w1;
    float aX = wh * lo16(v), aY = wh * hi16(v);
    float ps = 0.f;                  // low lanes: head0 partial; high: head1
    const float adh = lo ? adn.x : adn.y;

    const int beg = rowptr[n], end = rowptr[n + 1];
    for (int base = beg; base < end; base += 32) {
        int cnt = min(32, end - base);
        // stage: lane el owns edge el; low half computes head0 exp, high head1
        int sv = n;
        if (el < cnt) sv = csr_src[base + el];            // coalesced
        float av = asrc[(size_t)sv * 2 + (lo ? 0 : 1)];   // 4B gather
        float f = av + adh; f = f > 0.f ? f : 0.2f * f;
        float usel = (el < cnt) ? __expf(f) : 0.f;
        ps += usel;

        int k = 0;
        for (; k + 8 <= cnt; k += 8) {
#pragma unroll
            for (int j = 0; j < 8; ++j) {
                int e = k + j;
                int se = __builtin_amdgcn_readlane(sv, e);        // SGPR
                float su0 = rlane_f(usel, e);                     // SGPR (head0)
                float su1 = rlane_f(usel, e + 32);                // SGPR (head1)
                float uu = lo ? su0 : su1;                        // cndmask
                unsigned int vv = ((const unsigned int*)(h2 + (size_t)se * 128))[lane];
                aX = fmaf(uu, lo16(vv), aX);
                aY = fmaf(uu, hi16(vv), aY);
            }
        }
        for (; k < cnt; ++k) {
            int se = __builtin_amdgcn_readlane(sv, k);
            float su0 = rlane_f(usel, k);
            float su1 = rlane_f(usel, k + 32);
            float uu = lo ? su0 : su1;
            unsigned int vv = ((const unsigned int*)(h2 + (size_t)se * 128))[lane];
            aX = fmaf(uu, lo16(vv), aX);
            aY = fmaf(uu, hi16(vv), aY);
        }
    }

    // softmax denominators: reduce within each 32-lane half
#pragma unroll
    for (int off = 1; off <= 16; off <<= 1)
        ps += __shfl_xor(ps, off);
    float sdiv = ps + (lo ? w0 : w1);

    int j0 = lane * 2;
    float2 bv = *(const float2*)(bias + j0);
    float o0 = aX / sdiv + bv.x;
    float o1 = aY / sdiv + bv.y;
    int g = batch[n];
    atomicAdd(&pooled[(size_t)g * 128 + j0], o0);
    atomicAdd(&pooled[(size_t)g * 128 + j0 + 1], o1);
}

// ---------------- batchnorm stats over G graphs ----------------
__global__ __launch_bounds__(512) void k_bnstat(const float* __restrict__ pooled,
                                                const float* __restrict__ gamma,
                                                const float* __restrict__ beta,
                                                float* __restrict__ scale,
                                                float* __restrict__ shift, int G) {
    __shared__ float ls[512], lq[512];
    int t = threadIdx.x;
    int j = t & 127, q = t >> 7;
    int per = G >> 2;
    float sum = 0.f, sq = 0.f;
    for (int g = q * per; g < (q + 1) * per; ++g) {
        float v = pooled[g * 128 + j];
        sum += v; sq += v * v;
    }
    ls[t] = sum; lq[t] = sq;
    __syncthreads();
    if (t < 128) {
        sum = ls[t] + ls[t + 128] + ls[t + 256] + ls[t + 384];
        sq  = lq[t] + lq[t + 128] + lq[t + 256] + lq[t + 384];
        float mu = sum / (float)G;
        float var = sq / (float)G - mu * mu;
        float sc = gamma[t] * rsqrtf(var + 1e-5f);
        scale[t] = sc;
        shift[t] = beta[t] - mu * sc;
    }
}

// ---------------- norm + FC (block per graph) ----------------
__global__ __launch_bounds__(128) void k_fc(const float* __restrict__ pooled,
                                            const float* __restrict__ scale,
                                            const float* __restrict__ shift,
                                            const float* __restrict__ fcw,
                                            const float* __restrict__ fcb,
                                            float* __restrict__ out, int LAT) {
    __shared__ float nrm[128];
    int g = blockIdx.x;
    int t = threadIdx.x;
    nrm[t] = pooled[g * 128 + t] * scale[t] + shift[t];
    __syncthreads();
    if (t < LAT) {
        float acc = fcb[t];
#pragma unroll 8
        for (int j = 0; j < 128; ++j)
            acc = fmaf(nrm[j], fcw[t * 128 + j], acc);
        out[g * LAT + t] = acc;
    }
}

extern "C" void kernel_launch(void* const* d_in, const int* in_sizes, int n_in,
                              void* d_out, int out_size, void* d_ws, size_t ws_size,
                              hipStream_t stream) {
    const float* x     = (const float*)d_in[0];
    const int*   ei    = (const int*)d_in[1];
    const int*   batch = (const int*)d_in[2];
    const float* lin_w = (const float*)d_in[4];
    const float* att_s = (const float*)d_in[5];
    const float* att_d = (const float*)d_in[6];
    const float* bias  = (const float*)d_in[7];
    const float* gamma = (const float*)d_in[8];
    const float* beta  = (const float*)d_in[9];
    const float* fcw   = (const float*)d_in[10];
    const float* fcb   = (const float*)d_in[11];
    float* out = (float*)d_out;

    const int N   = in_sizes[2];
    const int E   = in_sizes[1] / 2;
    const int LAT = in_sizes[11];
    const int G   = out_size / LAT;
    const int NB  = (N + 255) >> BKT_SHIFT;

    char* ws = (char*)d_ws;
    unsigned short* h2 = (unsigned short*)ws; ws += (size_t)N * 128 * 2;
    unsigned short* wb = (unsigned short*)ws; ws += (size_t)128 * 128 * 2;
    float* asrc   = (float*)ws; ws += (size_t)N * 2 * 4;
    float* adst   = (float*)ws; ws += (size_t)N * 2 * 4;
    // zeroed region: bcnt | pooled (contiguous words)
    int*   bcnt   = (int*)ws;   ws += (size_t)NB * 4;
    float* pooled = (float*)ws; ws += (size_t)G * 128 * 4;
    float* scale  = (float*)ws; ws += 128 * 4;
    float* shift  = (float*)ws; ws += 128 * 4;
    int*   bbase  = (int*)ws;   ws += (size_t)(NB + 1) * 4;
    int*   bcur   = (int*)ws;   ws += (size_t)NB * 4;
    int*   rowptr = (int*)ws;   ws += (size_t)(N + 1) * 4;
    unsigned int* stage = (unsigned int*)ws; ws += (size_t)E * 4;
    int*   csr    = (int*)ws;   ws += (size_t)E * 4;

    long long nzero = (long long)NB + (long long)G * 128;
    k_zero<<<256, 256, 0, stream>>>((float*)bcnt, nzero);
    k_wcvt<<<64, 256, 0, stream>>>(lin_w, wb);

    k_lin<<<(N + 63) / 64, 256, 0, stream>>>(x, wb, att_s, att_d, h2, asrc, adst, N);
    int nbin = (E + BIN_TILE - 1) / BIN_TILE;
    k_b0<<<nbin, 256, 0, stream>>>(ei, E, bcnt, NB);
    k_bscan<<<1, 1024, 0, stream>>>(bcnt, bbase, bcur, NB, E);
    k_bin<<<nbin, 256, 0, stream>>>(ei, E, bcur, stage, NB);
    k_bsort<<<NB, 256, 0, stream>>>(bbase, stage, rowptr, csr, N, E);
    k_agg<<<(N + 3) / 4, 256, 0, stream>>>(rowptr, csr, h2, asrc, adst, bias, batch, pooled, N);
    k_bnstat<<<1, 512, 0, stream>>>(pooled, gamma, beta, scale, shift, G);
    k_fc<<<G, 128, 0, stream>>>(pooled, scale, shift, fcw, fcb, out, LAT);
}